// Round 7
// baseline (658.694 us; speedup 1.0000x reference)
//
#include <hip/hip_runtime.h>
#include <stdint.h>

#define NE 64
#define NT 2048
#define NH 512
#define NI 1024

typedef __attribute__((ext_vector_type(8))) short bf16x8;
typedef __attribute__((ext_vector_type(4))) float f32x4;
typedef __attribute__((ext_vector_type(16))) float f32x16;

typedef const __attribute__((address_space(1))) void* gptr1_t;
typedef __attribute__((address_space(3))) void* lptr3_t;
#define GLOAD16(g, l) \
  __builtin_amdgcn_global_load_lds((gptr1_t)(const void*)(g), (lptr3_t)(void*)(l), 16, 0, 0)

static __device__ __forceinline__ uint16_t f2bf(float f) {
  uint32_t u = __builtin_bit_cast(uint32_t, f);
  u += 0x7fffu + ((u >> 16) & 1u);
  return (uint16_t)(u >> 16);
}

static __device__ __forceinline__ float gelu_erf(float v) {
  return 0.5f * v * (1.0f + erff(v * 0.7071067811865475f));
}

// ---------------------------------------------------------------------------
// Fused weight prep: transpose + cast both wi and wo in one launch.
// blocks [0, 8192): wi[e][K=512][N=1024] -> wiB[e][n][k]
// blocks [8192, 16384): wo[e][K=1024][N=512] -> woB[e][n][k]
// ---------------------------------------------------------------------------
__global__ __launch_bounds__(256)
void conv_both(const float* __restrict__ wi, const float* __restrict__ wo,
               uint16_t* __restrict__ wiB, uint16_t* __restrict__ woB) {
  int id = blockIdx.x;
  const float* in;
  uint16_t* out;
  int K, N, k0, n0, e;
  if (id < NE * 128) {
    e = id >> 7;
    const int rem = id & 127;
    k0 = (rem >> 4) << 6;  // 8 k-tiles (K=512)
    n0 = (rem & 15) << 6;  // 16 n-tiles (N=1024)
    in = wi; out = wiB; K = NH; N = NI;
  } else {
    id -= NE * 128;
    e = id >> 7;
    const int rem = id & 127;
    k0 = (rem >> 3) << 6;  // 16 k-tiles (K=1024)
    n0 = (rem & 7) << 6;   // 8 n-tiles (N=512)
    in = wo; out = woB; K = NI; N = NH;
  }
  __shared__ uint16_t t[64][72];
  const int tid = threadIdx.x;
  const int r = tid >> 2;
  const int c0 = (tid & 3) << 4;
  const float* ip = in + ((size_t)e * K + k0 + r) * N + n0 + c0;
#pragma unroll
  for (int j = 0; j < 16; j += 4) {
    f32x4 v = *(const f32x4*)(ip + j);
#pragma unroll
    for (int u = 0; u < 4; ++u) t[c0 + j + u][r] = f2bf(v[u]);
  }
  __syncthreads();
  uint16_t* op = out + ((size_t)e * N + n0 + r) * K + k0 + c0;
  *(bf16x8*)op = *(const bf16x8*)&t[r][c0];
  *(bf16x8*)(op + 8) = *(const bf16x8*)&t[r][c0 + 8];
}

// ---------------------------------------------------------------------------
// GEMM1 + GELU: h[e,t,i] = gelu( x[t,e,:] . wi'[e,i,:] ), bf16 out.
// m97 structure, 128x128x64 tile, single 32 KiB LDS/operand, 2 barriers/K-step.
// A: fp32 x -> regs -> f2bf -> swizzled ds_write_b128 (cast fused in; no xB).
//    Next-tile f32 loads issued AFTER the compute barrier so the MFMA cluster
//    hides their latency; regs carried across the cluster.
// B: global_load_lds, XOR-swizzled SOURCE, linear LDS dest.
// LDS layout: elem (r,k) at r*64 + ((k>>3)^(r&7))*8 + (k&7).
// ---------------------------------------------------------------------------
__global__ __launch_bounds__(256, 4)
void k_gemm1(const float* __restrict__ x, const uint16_t* __restrict__ wiB,
             uint16_t* __restrict__ h, int t_start, int Ts) {
  const int Mt = Ts >> 7;
  const int nwg = gridDim.x;  // Mt*8*64, divisible by 8
  const int wid = (blockIdx.x & 7) * (nwg >> 3) + (blockIdx.x >> 3);
  const int bn = wid & 7;
  const int bm = (wid >> 3) % Mt;
  const int be = wid / (Mt << 3);
  const int t0 = bm << 7, n0 = bn << 7;

  __shared__ __align__(16) uint16_t As[8192];
  __shared__ __align__(16) uint16_t Bs[8192];

  const int tid = threadIdx.x, lane = tid & 63;
  const int wy = (tid >> 7) & 1, wx = (tid >> 6) & 1;

  const uint16_t* Bbase = wiB + ((size_t)be * NI + n0) * NH;

  int boff[4], ldsOff[4], aLds[4];
  const float* aP[4];
#pragma unroll
  for (int s = 0; s < 4; ++s) {
    const int c = (s << 8) + tid;
    const int rr = c >> 3, kgs = c & 7;
    boff[s] = rr * NH + ((kgs ^ (rr & 7)) << 3);
    ldsOff[s] = c << 4;
    aP[s] = x + ((size_t)(t_start + t0 + rr) * NE + be) * NH + (kgs << 3);
    aLds[s] = (rr << 6) + ((kgs ^ (rr & 7)) << 3);
  }

  f32x4 ar[4][2];
  f32x4 acc[4][4];
#pragma unroll
  for (int i = 0; i < 4; ++i)
#pragma unroll
    for (int j = 0; j < 4; ++j) acc[i][j] = (f32x4){0.f, 0.f, 0.f, 0.f};

  auto loadA = [&](int it) {
#pragma unroll
    for (int s = 0; s < 4; ++s) {
      ar[s][0] = *(const f32x4*)(aP[s] + (it << 6));
      ar[s][1] = *(const f32x4*)(aP[s] + (it << 6) + 4);
    }
  };
  auto writeA = [&]() {
#pragma unroll
    for (int s = 0; s < 4; ++s) {
      bf16x8 w;
#pragma unroll
      for (int u = 0; u < 4; ++u) {
        w[u] = (short)f2bf(ar[s][0][u]);
        w[u + 4] = (short)f2bf(ar[s][1][u]);
      }
      *(bf16x8*)&As[aLds[s]] = w;
    }
  };

  loadA(0);
  const int KIT = NH >> 6;  // 8
  for (int it = 0; it < KIT; ++it) {
    __syncthreads();  // all waves done reading LDS
    writeA();         // regs (tile it) -> swizzled LDS
#pragma unroll
    for (int s = 0; s < 4; ++s)
      GLOAD16(Bbase + (it << 6) + boff[s], (char*)Bs + ldsOff[s]);
    __syncthreads();  // drains ds_write + gload_lds
    if (it + 1 < KIT) loadA(it + 1);  // f32 prefetch hides under MFMAs
#pragma unroll
    for (int ks = 0; ks < 2; ++ks) {
      const int kg = (ks << 2) + (lane >> 4);
      bf16x8 af[4], bfr[4];
#pragma unroll
      for (int mi = 0; mi < 4; ++mi) {
        const int row = (wy << 6) + (mi << 4) + (lane & 15);
        af[mi] = *(const bf16x8*)&As[(row << 6) + ((kg ^ (row & 7)) << 3)];
      }
#pragma unroll
      for (int ni = 0; ni < 4; ++ni) {
        const int col = (wx << 6) + (ni << 4) + (lane & 15);
        bfr[ni] = *(const bf16x8*)&Bs[(col << 6) + ((kg ^ (col & 7)) << 3)];
      }
#pragma unroll
      for (int mi = 0; mi < 4; ++mi)
#pragma unroll
        for (int ni = 0; ni < 4; ++ni)
          acc[mi][ni] = __builtin_amdgcn_mfma_f32_16x16x32_bf16(
              af[mi], bfr[ni], acc[mi][ni], 0, 0, 0);
    }
  }

#pragma unroll
  for (int mi = 0; mi < 4; ++mi) {
#pragma unroll
    for (int ni = 0; ni < 4; ++ni) {
      const int col = n0 + (wx << 6) + (ni << 4) + (lane & 15);
#pragma unroll
      for (int j = 0; j < 4; ++j) {
        const int r = t0 + (wy << 6) + (mi << 4) + ((lane >> 4) << 2) + j;
        h[((size_t)be * Ts + r) * NI + col] = f2bf(gelu_erf(acc[mi][ni][j]));
      }
    }
  }
}

// ---------------------------------------------------------------------------
// GEMM2: out[t,e,hc] = h[e,t,:] . wo'[e,hc,:], fp32 out. m97 staging,
// 32x32x16 MFMA, 2x2 tiles/wave. C: col=lane&31, row=(reg&3)+8*(reg>>2)+4*(lane>>5).
// ---------------------------------------------------------------------------
__global__ __launch_bounds__(256, 4)
void k_gemm2(const uint16_t* __restrict__ hA, const uint16_t* __restrict__ woB,
             float* __restrict__ out, int t_start, int Ts) {
  const int Mt = Ts >> 7;
  const int nwg = gridDim.x;  // Mt*4*64
  const int wid = (blockIdx.x & 7) * (nwg >> 3) + (blockIdx.x >> 3);
  const int bn = wid & 3;
  const int bm = (wid >> 2) % Mt;
  const int be = wid / (Mt << 2);
  const int t0 = bm << 7, n0 = bn << 7;

  __shared__ __align__(16) uint16_t As[8192];
  __shared__ __align__(16) uint16_t Bs[8192];

  const int tid = threadIdx.x, lane = tid & 63;
  const int wy = (tid >> 7) & 1, wx = (tid >> 6) & 1;
  const int l31 = lane & 31, l5 = lane >> 5;

  const uint16_t* Abase = hA + ((size_t)be * Ts + t0) * NI;
  const uint16_t* Bbase = woB + ((size_t)be * NH + n0) * NI;

  int off[4], ldsOff[4];
#pragma unroll
  for (int s = 0; s < 4; ++s) {
    const int c = (s << 8) + tid;
    const int rr = c >> 3, kgs = c & 7;
    off[s] = (rr << 10) + ((kgs ^ (rr & 7)) << 3);
    ldsOff[s] = c << 4;
  }

  f32x16 acc[2][2];
#pragma unroll
  for (int i = 0; i < 2; ++i)
#pragma unroll
    for (int j = 0; j < 2; ++j)
#pragma unroll
      for (int u = 0; u < 16; ++u) acc[i][j][u] = 0.f;

  const int KIT = NI >> 6;  // 16
  for (int it = 0; it < KIT; ++it) {
    __syncthreads();
#pragma unroll
    for (int s = 0; s < 4; ++s)
      GLOAD16(Abase + (it << 6) + off[s], (char*)As + ldsOff[s]);
#pragma unroll
    for (int s = 0; s < 4; ++s)
      GLOAD16(Bbase + (it << 6) + off[s], (char*)Bs + ldsOff[s]);
    __syncthreads();
#pragma unroll
    for (int ks = 0; ks < 4; ++ks) {
      const int kg = (ks << 1) + l5;
      bf16x8 af[2], bfr[2];
#pragma unroll
      for (int mi = 0; mi < 2; ++mi) {
        const int row = (wy << 6) + (mi << 5) + l31;
        af[mi] = *(const bf16x8*)&As[(row << 6) + ((kg ^ (row & 7)) << 3)];
      }
#pragma unroll
      for (int ni = 0; ni < 2; ++ni) {
        const int col = (wx << 6) + (ni << 5) + l31;
        bfr[ni] = *(const bf16x8*)&Bs[(col << 6) + ((kg ^ (col & 7)) << 3)];
      }
#pragma unroll
      for (int mi = 0; mi < 2; ++mi)
#pragma unroll
        for (int ni = 0; ni < 2; ++ni)
          acc[mi][ni] = __builtin_amdgcn_mfma_f32_32x32x16_bf16(
              af[mi], bfr[ni], acc[mi][ni], 0, 0, 0);
    }
  }

#pragma unroll
  for (int mi = 0; mi < 2; ++mi) {
#pragma unroll
    for (int ni = 0; ni < 2; ++ni) {
      const int col = n0 + (wx << 6) + (ni << 5) + l31;
#pragma unroll
      for (int g = 0; g < 4; ++g) {
#pragma unroll
        for (int j = 0; j < 4; ++j) {
          const int row = t0 + (wy << 6) + (mi << 5) + (g << 3) + (l5 << 2) + j;
          out[((size_t)(t_start + row) * NE + be) * NH + col] =
              acc[mi][ni][(g << 2) + j];
        }
      }
    }
  }
}

extern "C" void kernel_launch(void* const* d_in, const int* in_sizes, int n_in,
                              void* d_out, int out_size, void* d_ws, size_t ws_size,
                              hipStream_t stream) {
  const float* x = (const float*)d_in[0];   // [T, E, H] fp32
  const float* wi = (const float*)d_in[1];  // [E, H, I] fp32
  const float* wo = (const float*)d_in[2];  // [E, I, H] fp32
  float* out = (float*)d_out;

  // ws: wiB bf16 [E][I][H] (64MiB) | woB bf16 [E][H][I] (64MiB) | h slice
  uint16_t* wiB = (uint16_t*)d_ws;
  uint16_t* woB = (uint16_t*)((char*)d_ws + 67108864);
  uint16_t* h = (uint16_t*)((char*)d_ws + 134217728);

  // Ts=512: h slice 64 MiB; slice working set (~h + x-slice + weights) fits
  // the 256 MiB Infinity Cache, so gemm1->gemm2 h traffic stays on-die.
  const size_t perRow = (size_t)NE * NI * 2;  // 128 KiB
  size_t avail = (ws_size > 134217728u) ? ws_size - 134217728u : 0;
  int Ts = (int)(avail / perRow);
  if (Ts > 512) Ts = 512;
  Ts &= ~127;
  if (Ts < 128) Ts = 128;

  hipLaunchKernelGGL(conv_both, dim3(2 * NE * 128), dim3(256), 0, stream,
                     wi, wo, wiB, woB);

  for (int ts = 0; ts < NT; ts += Ts) {
    int cur = NT - ts;
    if (cur > Ts) cur = Ts;
    const int Mt = cur >> 7;
    hipLaunchKernelGGL(k_gemm1, dim3(Mt * 8 * NE), dim3(256), 0, stream,
                       x, wiB, h, ts, cur);
    hipLaunchKernelGGL(k_gemm2, dim3(Mt * 4 * NE), dim3(256), 0, stream,
                       h, woB, out, ts, cur);
  }
}